// Round 1
// baseline (571.940 us; speedup 1.0000x reference)
//
#include <hip/hip_runtime.h>

#define NEG_SLOPE 0.2f

// Fixed-point scales for the packed 64-bit atomic accumulator.
// low 32 bits  : denominator (always-positive, monotone -> no carry into high word
//                as long as final sum < 2^32; worst case ~3000*2^19 = 1.6e9. OK)
// high 32 bits : numerator, signed two's complement (carry-isolated from low word)
#define DEN_SCALE 524288.0f     // 2^19
#define NUM_SCALE 32768.0f      // 2^15
#define INV_DEN_SCALE (1.0f / 524288.0f)
#define INV_NUM_SCALE (1.0f / 32768.0f)

typedef float v4f __attribute__((ext_vector_type(4)));
typedef int   v4i __attribute__((ext_vector_type(4)));

// -------- Kernel 1: x[row] = dot(F[row, :], W)  (one 64-lane wave per row) --------
// f4[lane + 64*k]: each load instruction is a fully coalesced 1 KB wave access.
// F is streamed once -> non-temporal so it doesn't pollute L2 (x stays resident
// for the edge kernel).
__global__ void gemv_rowdot(const float* __restrict__ F, const float* __restrict__ W,
                            float* __restrict__ x, int n, int d) {
    int wave = (blockIdx.x * blockDim.x + threadIdx.x) >> 6;
    int lane = threadIdx.x & 63;
    if (wave >= n) return;
    const v4f* f4 = (const v4f*)(F + (size_t)wave * d);
    const v4f* w4 = (const v4f*)W;
    int nv = d >> 2;                       // 128 float4s per row (d=512)
    float s = 0.f;
    #pragma unroll 2
    for (int k = lane; k < nv; k += 64) {
        v4f a = __builtin_nontemporal_load(&f4[k]);
        v4f b = w4[k];                     // W reused by all waves: keep cacheable
        s += a.x * b.x + a.y * b.y + a.z * b.z + a.w * b.w;
    }
    #pragma unroll
    for (int off = 32; off; off >>= 1) s += __shfl_down(s, off, 64);
    if (lane == 0) x[wave] = s;
}

// -------- per-edge body: exp(lrelu) -> ONE u64 fixed-point atomic ----
__device__ __forceinline__ void edge_one(float xs, float xd, float as, float ad,
                                         int d, unsigned long long* __restrict__ acc) {
    float v = xs * as + xd * ad;
    float logit = v > 0.f ? v : NEG_SLOPE * v;
    float e = __expf(logit);               // logits are O(1); fast exp is exact enough
    unsigned int den_fx = (unsigned int)__float2int_rn(e * DEN_SCALE);
    int          num_fx = __float2int_rn(e * xs * NUM_SCALE);
    unsigned long long upd =
        ((unsigned long long)(unsigned int)num_fx << 32) | (unsigned long long)den_fx;
    atomicAdd(&acc[d], upd);
}

// -------- Kernel 2a: 4 edges per thread --------
// - edge-index loads are dwordx4 AND non-temporal: the 51.2 MB stream must not
//   evict the 400 KB x / 800 KB acc working sets from L2 (that eviction forces
//   12.8M gather misses to L3/HBM = ~0.8 GB of line refills).
// - 8 independent gathers + 4 atomics in flight per thread (4x the MLP of the
//   one-edge-per-thread version).
__global__ void edge_accum4(const int* __restrict__ ei, const float* __restrict__ x,
                            const float* __restrict__ att_src_p,
                            const float* __restrict__ att_dst_p,
                            unsigned long long* __restrict__ acc, int nedges) {
    int nq = nedges >> 2;
    int i = blockIdx.x * blockDim.x + threadIdx.x;
    if (i >= nq) return;
    const v4i* s4 = (const v4i*)ei;
    const v4i* d4 = (const v4i*)(ei + nedges);   // requires nedges % 4 == 0 (host-checked)
    v4i s = __builtin_nontemporal_load(&s4[i]);
    v4i d = __builtin_nontemporal_load(&d4[i]);
    float as = *att_src_p, ad = *att_dst_p;
    // issue all 8 gathers before any compute -> max memory-level parallelism
    float xs0 = x[s.x], xs1 = x[s.y], xs2 = x[s.z], xs3 = x[s.w];
    float xd0 = x[d.x], xd1 = x[d.y], xd2 = x[d.z], xd3 = x[d.w];
    edge_one(xs0, xd0, as, ad, d.x, acc);
    edge_one(xs1, xd1, as, ad, d.y, acc);
    edge_one(xs2, xd2, as, ad, d.z, acc);
    edge_one(xs3, xd3, as, ad, d.w, acc);
}

// -------- Kernel 2b: scalar fallback (only used if nedges % 4 != 0) --------
__global__ void edge_accum1(const int* __restrict__ ei, const float* __restrict__ x,
                            const float* __restrict__ att_src_p,
                            const float* __restrict__ att_dst_p,
                            unsigned long long* __restrict__ acc, int nedges) {
    int i = blockIdx.x * blockDim.x + threadIdx.x;
    if (i >= nedges) return;
    int s = ei[i], d = ei[nedges + i];
    float as = *att_src_p, ad = *att_dst_p;
    edge_one(x[s], x[d], as, ad, d, acc);
}

// -------- Kernel 3: out = (num + e_self*x) / (den + e_self) + bias --------
// (self-loops folded here instead of 100K extra atomics)
__global__ void finalize(const unsigned long long* __restrict__ acc,
                         const float* __restrict__ x,
                         const float* __restrict__ att_src_p,
                         const float* __restrict__ att_dst_p,
                         const float* __restrict__ bias, float* __restrict__ out, int n) {
    int i = blockIdx.x * blockDim.x + threadIdx.x;
    if (i >= n) return;
    float xi = x[i];
    float v = xi * (*att_src_p + *att_dst_p);      // self-loop logit
    float logit = v > 0.f ? v : NEG_SLOPE * v;
    float es = __expf(logit);
    unsigned long long a = acc[i];
    float num = (float)(int)(a >> 32) * INV_NUM_SCALE;
    float den = (float)(unsigned int)(a & 0xFFFFFFFFull) * INV_DEN_SCALE;
    out[i] = (num + es * xi) / (den + es) + *bias;
}

extern "C" void kernel_launch(void* const* d_in, const int* in_sizes, int n_in,
                              void* d_out, int out_size, void* d_ws, size_t ws_size,
                              hipStream_t stream) {
    const float* F       = (const float*)d_in[0];
    const int*   ei      = (const int*)d_in[1];
    const float* W       = (const float*)d_in[2];
    const float* att_src = (const float*)d_in[3];
    const float* att_dst = (const float*)d_in[4];
    const float* bias    = (const float*)d_in[5];
    float* out = (float*)d_out;

    int d = in_sizes[2];              // 512
    int n = in_sizes[0] / d;          // 100000
    int e = in_sizes[1] / 2;          // 6400000

    float* x = (float*)d_ws;                                // [n] floats
    unsigned long long* acc = (unsigned long long*)(x + n); // [n] u64 (n*4 is 8B-aligned)

    // ws is re-poisoned 0xAA before every timed launch -> zero the accumulators
    (void)hipMemsetAsync(acc, 0, (size_t)n * sizeof(unsigned long long), stream);

    gemv_rowdot<<<(n + 3) / 4, 256, 0, stream>>>(F, W, x, n, d);

    if ((e & 3) == 0 && e > 0) {
        int nq = e >> 2;
        edge_accum4<<<(nq + 255) / 256, 256, 0, stream>>>(ei, x, att_src, att_dst,
                                                          acc, e);
    } else {
        edge_accum1<<<(e + 255) / 256, 256, 0, stream>>>(ei, x, att_src, att_dst,
                                                         acc, e);
    }

    finalize<<<(n + 255) / 256, 256, 0, stream>>>(acc, x, att_src, att_dst, bias, out, n);
}

// Round 2
// 377.456 us; speedup vs baseline: 1.5152x; 1.5152x over previous
//
#include <hip/hip_runtime.h>

#define NEG_SLOPE 0.2f

// Fixed-point scales (identical to the atomic version -> bit-identical sums).
// Accumulator u64: hi 32 = num (s16.15, two's complement), lo 32 = den (u13.19).
#define DEN_SCALE 524288.0f     // 2^19
#define NUM_SCALE 32768.0f      // 2^15
#define INV_DEN_SCALE (1.0f / 524288.0f)
#define INV_NUM_SCALE (1.0f / 32768.0f)

// Binning geometry: dst space split into bins of RSZ; phase-2 LDS acc = RSZ*8 = 32 KB.
#define RBITS 12
#define RSZ   4096
#define MAXNB 64                // supports n <= 262144
#define SSUB  16                // sub-blocks per bin in phase 2
#define EPT   8                 // edges per thread in phase 1
#define P1BLK 256
#define CHUNK (P1BLK * EPT)     // 2048 edges per block

typedef float v4f __attribute__((ext_vector_type(4)));
typedef int   v4i __attribute__((ext_vector_type(4)));
typedef unsigned long long u64;
typedef unsigned int u32;

// -------- Kernel 1: x[row] = dot(F[row,:], W) (one wave per row, coalesced) --------
__global__ void gemv_rowdot(const float* __restrict__ F, const float* __restrict__ W,
                            float* __restrict__ x, int n, int d) {
    int wave = (blockIdx.x * blockDim.x + threadIdx.x) >> 6;
    int lane = threadIdx.x & 63;
    if (wave >= n) return;
    const v4f* f4 = (const v4f*)(F + (size_t)wave * d);
    const v4f* w4 = (const v4f*)W;
    int nv = d >> 2;
    float s = 0.f;
    #pragma unroll 2
    for (int k = lane; k < nv; k += 64) {
        v4f a = __builtin_nontemporal_load(&f4[k]);   // F streamed once: keep L2 for x
        v4f b = w4[k];
        s += a.x * b.x + a.y * b.y + a.z * b.z + a.w * b.w;
    }
    #pragma unroll
    for (int off = 32; off; off >>= 1) s += __shfl_down(s, off, 64);
    if (lane == 0) x[wave] = s;
}

// Packed per-edge payload: bits[0:12) dst_low, [12:38) den u26 (u7.19), [38:64) num s26 (s11.15)
__device__ __forceinline__ u64 pack_edge(float e, float xs, int dlow) {
    int den = __float2int_rn(e * DEN_SCALE);
    den = min(den, (1 << 26) - 1);                      // clamp (never hit for sane logits)
    int num = __float2int_rn(e * xs * NUM_SCALE);
    num = max(min(num, (1 << 25) - 1), -((1 << 25) - 1));
    return (u64)(u32)dlow | ((u64)(u32)den << RBITS) | ((u64)((u32)num & 0x3FFFFFFu) << 38);
}

// -------- Phase 1: compute per-edge payload, scatter into dst bins --------
// Per block: local LDS histogram -> one global atomicAdd per (block,bin) to reserve a
// contiguous window -> plain (non-atomic) u64 stores. ~78K far atomics total vs 6.4M.
__global__ __launch_bounds__(P1BLK)
void bucket_scatter(const int* __restrict__ ei, const float* __restrict__ x,
                    const float* __restrict__ att_src_p, const float* __restrict__ att_dst_p,
                    u64* __restrict__ binbuf, u32* __restrict__ cnt,
                    u64* __restrict__ acc, int nedges, int nb, int capb) {
    __shared__ u32 lhist[MAXNB];
    __shared__ u32 lbase[MAXNB];
    const int tid = threadIdx.x;
    for (int b = tid; b < nb; b += P1BLK) lhist[b] = 0;
    __syncthreads();

    const long long base_e = (long long)blockIdx.x * CHUNK + (long long)tid * EPT;
    const float as = *att_src_p, ad = *att_dst_p;

    int se[EPT], de[EPT];
    if (((nedges & 3) == 0) && (base_e + EPT <= nedges)) {
        const v4i* sp = (const v4i*)(ei + base_e);
        const v4i* dp = (const v4i*)(ei + (size_t)nedges + base_e);
        v4i a0 = sp[0], a1 = sp[1], b0 = dp[0], b1 = dp[1];
        se[0] = a0.x; se[1] = a0.y; se[2] = a0.z; se[3] = a0.w;
        se[4] = a1.x; se[5] = a1.y; se[6] = a1.z; se[7] = a1.w;
        de[0] = b0.x; de[1] = b0.y; de[2] = b0.z; de[3] = b0.w;
        de[4] = b1.x; de[5] = b1.y; de[6] = b1.z; de[7] = b1.w;
    } else {
        #pragma unroll
        for (int t = 0; t < EPT; ++t) {
            long long idx = base_e + t;
            if (idx < nedges) { se[t] = ei[idx]; de[t] = ei[(size_t)nedges + idx]; }
            else { se[t] = -1; de[t] = -1; }
        }
    }

    float xs[EPT], xd[EPT];
    #pragma unroll
    for (int t = 0; t < EPT; ++t)
        if (se[t] >= 0) { xs[t] = x[se[t]]; xd[t] = x[de[t]]; }

    u64 pk[EPT]; u32 rk[EPT]; int bn[EPT];
    #pragma unroll
    for (int t = 0; t < EPT; ++t) {
        if (se[t] >= 0) {
            float v = xs[t] * as + xd[t] * ad;
            float logit = v > 0.f ? v : NEG_SLOPE * v;
            float e = __expf(logit);
            bn[t] = de[t] >> RBITS;
            pk[t] = pack_edge(e, xs[t], de[t] & (RSZ - 1));
            rk[t] = atomicAdd(&lhist[bn[t]], 1u);        // LDS: arrival rank within block
        } else {
            bn[t] = -1;
        }
    }
    __syncthreads();
    if (tid < nb) lbase[tid] = atomicAdd(&cnt[tid], lhist[tid]);   // reserve window
    __syncthreads();
    #pragma unroll
    for (int t = 0; t < EPT; ++t) {
        if (bn[t] >= 0) {
            u32 slot = lbase[bn[t]] + rk[t];
            if (slot < (u32)capb) {
                binbuf[(size_t)bn[t] * (size_t)capb + slot] = pk[t];  // plain cached store
            } else {
                // capacity overflow (only for adversarial dst skew): stay correct via
                // the old direct far-atomic path.
                int num = (int)((long long)pk[t] >> 38);
                u32 den = (u32)((pk[t] >> RBITS) & 0x3FFFFFFu);
                int dd = (bn[t] << RBITS) | (int)(pk[t] & (u64)(RSZ - 1));
                atomicAdd(&acc[dd], ((u64)(u32)num << 32) | (u64)den);
            }
        }
    }
}

// -------- Phase 2: per-bin LDS accumulation (ds_add_u64), non-atomic partial write ----
__global__ __launch_bounds__(1024)
void bin_reduce(const u64* __restrict__ binbuf, const u32* __restrict__ cnt,
                u64* __restrict__ partial, int nb, int capb) {
    __shared__ u64 lacc[RSZ];                       // 32 KB
    const int b = blockIdx.x / SSUB;
    const int s = blockIdx.x % SSUB;
    const int tid = threadIdx.x;
    #pragma unroll
    for (int r = tid; r < RSZ; r += 1024) lacc[r] = 0ull;
    __syncthreads();

    u32 cb = cnt[b];
    if (cb > (u32)capb) cb = (u32)capb;
    u32 lo = (u32)(((u64)cb * (u32)s) / SSUB);
    u32 hi = (u32)(((u64)cb * (u32)(s + 1)) / SSUB);
    const u64* src = binbuf + (size_t)b * (size_t)capb;
    for (u32 k = lo + tid; k < hi; k += 1024) {
        u64 p = src[k];
        u32 r   = (u32)(p & (u64)(RSZ - 1));
        u32 den = (u32)((p >> RBITS) & 0x3FFFFFFu);
        int num = (int)((long long)p >> 38);        // sign-extended s26
        atomicAdd(&lacc[r], ((u64)(u32)num << 32) | (u64)den);   // LDS atomic
    }
    __syncthreads();
    u64* dstp = partial + (size_t)blockIdx.x * RSZ;
    #pragma unroll
    for (int r = tid; r < RSZ; r += 1024) dstp[r] = lacc[r];
}

// -------- Phase 3: sum SSUB partials + overflow acc + self-loop, write out --------
__global__ void finalize2(const u64* __restrict__ partial, const u64* __restrict__ acc,
                          const float* __restrict__ x,
                          const float* __restrict__ att_src_p,
                          const float* __restrict__ att_dst_p,
                          const float* __restrict__ bias, float* __restrict__ out, int n) {
    int i = blockIdx.x * blockDim.x + threadIdx.x;
    if (i >= n) return;
    int b = i >> RBITS, r = i & (RSZ - 1);
    u64 t = acc[i];
    const u64* pp = partial + ((size_t)b * SSUB) * RSZ + r;
    #pragma unroll
    for (int s = 0; s < SSUB; ++s) t += pp[(size_t)s * RSZ];
    float xi = x[i];
    float v = xi * (*att_src_p + *att_dst_p);       // self-loop logit
    float logit = v > 0.f ? v : NEG_SLOPE * v;
    float es = __expf(logit);
    float num = (float)(int)(t >> 32) * INV_NUM_SCALE;
    float den = (float)(u32)(t & 0xFFFFFFFFull) * INV_DEN_SCALE;
    out[i] = (num + es * xi) / (den + es) + *bias;
}

// ================= fallback path (ws too small): original far-atomic version =========
__device__ __forceinline__ void edge_one(float xs, float xd, float as, float ad,
                                         int d, u64* __restrict__ acc) {
    float v = xs * as + xd * ad;
    float logit = v > 0.f ? v : NEG_SLOPE * v;
    float e = __expf(logit);
    u32 den_fx = (u32)__float2int_rn(e * DEN_SCALE);
    int num_fx = __float2int_rn(e * xs * NUM_SCALE);
    atomicAdd(&acc[d], ((u64)(u32)num_fx << 32) | (u64)den_fx);
}

__global__ void edge_accum4(const int* __restrict__ ei, const float* __restrict__ x,
                            const float* __restrict__ att_src_p,
                            const float* __restrict__ att_dst_p,
                            u64* __restrict__ acc, int nedges) {
    int nq = nedges >> 2;
    int i = blockIdx.x * blockDim.x + threadIdx.x;
    if (i >= nq) return;
    const v4i* s4 = (const v4i*)ei;
    const v4i* d4 = (const v4i*)(ei + nedges);
    v4i s = s4[i], d = d4[i];
    float as = *att_src_p, ad = *att_dst_p;
    float xs0 = x[s.x], xs1 = x[s.y], xs2 = x[s.z], xs3 = x[s.w];
    float xd0 = x[d.x], xd1 = x[d.y], xd2 = x[d.z], xd3 = x[d.w];
    edge_one(xs0, xd0, as, ad, d.x, acc);
    edge_one(xs1, xd1, as, ad, d.y, acc);
    edge_one(xs2, xd2, as, ad, d.z, acc);
    edge_one(xs3, xd3, as, ad, d.w, acc);
}

__global__ void edge_accum1(const int* __restrict__ ei, const float* __restrict__ x,
                            const float* __restrict__ att_src_p,
                            const float* __restrict__ att_dst_p,
                            u64* __restrict__ acc, int nedges) {
    int i = blockIdx.x * blockDim.x + threadIdx.x;
    if (i >= nedges) return;
    int s = ei[i], d = ei[nedges + i];
    edge_one(x[s], x[d], *att_src_p, *att_dst_p, d, acc);
}

__global__ void finalize_atomic(const u64* __restrict__ acc, const float* __restrict__ x,
                                const float* __restrict__ att_src_p,
                                const float* __restrict__ att_dst_p,
                                const float* __restrict__ bias, float* __restrict__ out,
                                int n) {
    int i = blockIdx.x * blockDim.x + threadIdx.x;
    if (i >= n) return;
    float xi = x[i];
    float v = xi * (*att_src_p + *att_dst_p);
    float logit = v > 0.f ? v : NEG_SLOPE * v;
    float es = __expf(logit);
    u64 a = acc[i];
    float num = (float)(int)(a >> 32) * INV_NUM_SCALE;
    float den = (float)(u32)(a & 0xFFFFFFFFull) * INV_DEN_SCALE;
    out[i] = (num + es * xi) / (den + es) + *bias;
}

extern "C" void kernel_launch(void* const* d_in, const int* in_sizes, int n_in,
                              void* d_out, int out_size, void* d_ws, size_t ws_size,
                              hipStream_t stream) {
    const float* F       = (const float*)d_in[0];
    const int*   ei      = (const int*)d_in[1];
    const float* W       = (const float*)d_in[2];
    const float* att_src = (const float*)d_in[3];
    const float* att_dst = (const float*)d_in[4];
    const float* bias    = (const float*)d_in[5];
    float* out = (float*)d_out;

    int d = in_sizes[2];              // 512
    int n = in_sizes[0] / d;          // 100000
    int e = in_sizes[1] / 2;          // 6400000

    int nb = (n + RSZ - 1) >> RBITS;  // 25 bins
    // bin capacity: expected + ~6% + fixed slack (40 sigma for uniform-random dst)
    size_t capb_s = ((size_t)e * RSZ) / (size_t)n;
    capb_s += capb_s / 16 + 4096;
    int capb = (int)capb_s;

    // workspace layout
    size_t off_x   = 0;
    size_t off_acc = ((size_t)n * 4 + 7) & ~(size_t)7;
    size_t off_cnt = off_acc + (size_t)n * 8;
    size_t off_par = (off_cnt + (size_t)nb * 4 + 7) & ~(size_t)7;
    size_t off_bin = off_par + (size_t)nb * SSUB * RSZ * 8;
    size_t needed  = off_bin + (size_t)nb * capb_s * 8;

    float* x  = (float*)((char*)d_ws + off_x);
    u64* acc  = (u64*)((char*)d_ws + off_acc);
    u32* cnt  = (u32*)((char*)d_ws + off_cnt);
    u64* par  = (u64*)((char*)d_ws + off_par);
    u64* bin  = (u64*)((char*)d_ws + off_bin);

    bool fast = (nb <= MAXNB) && (needed <= ws_size) && (e > 0) && (n > 0);

    gemv_rowdot<<<(n + 3) / 4, 256, 0, stream>>>(F, W, x, n, d);

    if (fast) {
        // zero acc (overflow fallback) + cnt in one memset (adjacent)
        (void)hipMemsetAsync(acc, 0, (size_t)n * 8 + (size_t)nb * 4, stream);
        int nblk1 = (int)(((long long)e + CHUNK - 1) / CHUNK);
        bucket_scatter<<<nblk1, P1BLK, 0, stream>>>(ei, x, att_src, att_dst,
                                                    bin, cnt, acc, e, nb, capb);
        bin_reduce<<<nb * SSUB, 1024, 0, stream>>>(bin, cnt, par, nb, capb);
        finalize2<<<(n + 255) / 256, 256, 0, stream>>>(par, acc, x, att_src, att_dst,
                                                       bias, out, n);
    } else {
        (void)hipMemsetAsync(acc, 0, (size_t)n * 8, stream);
        if (e > 0) {
            if ((e & 3) == 0) {
                edge_accum4<<<((e >> 2) + 255) / 256, 256, 0, stream>>>(
                    ei, x, att_src, att_dst, acc, e);
            } else {
                edge_accum1<<<(e + 255) / 256, 256, 0, stream>>>(
                    ei, x, att_src, att_dst, acc, e);
            }
        }
        finalize_atomic<<<(n + 255) / 256, 256, 0, stream>>>(acc, x, att_src, att_dst,
                                                             bias, out, n);
    }
}

// Round 3
// 362.867 us; speedup vs baseline: 1.5762x; 1.0402x over previous
//
#include <hip/hip_runtime.h>

#define NEG_SLOPE 0.2f

// Fixed-point scales (identical across all versions -> bit-identical integer sums).
// Accumulator u64: hi 32 = num (s16.15, two's complement), lo 32 = den (u13.19).
#define DEN_SCALE 524288.0f     // 2^19
#define NUM_SCALE 32768.0f      // 2^15
#define INV_DEN_SCALE (1.0f / 524288.0f)
#define INV_NUM_SCALE (1.0f / 32768.0f)

// Binning geometry
#define RBITS 12
#define RSZ   4096
#define MAXNB 64                // n <= 262144 bins-wise; packing needs n <= 2^20
#define SSUB  20                // 25 bins * 20 = 500 blocks -> 97.6% CU balance
#define EPT   16                // edges per thread, phase 1
#define P1BLK 256
#define CHUNK (P1BLK * EPT)     // 4096 edges per scatter block
#define P2BLK 1024

typedef float v4f __attribute__((ext_vector_type(4)));
typedef int   v4i __attribute__((ext_vector_type(4)));
typedef unsigned long long u64;
typedef unsigned int u32;

// ---------------- shared device helpers ----------------
__device__ __forceinline__ void edge_one(float xs, float xd, float as, float ad,
                                         int d, u64* __restrict__ acc) {
    float v = xs * as + xd * ad;
    float logit = v > 0.f ? v : NEG_SLOPE * v;
    float e = __expf(logit);
    u32 den_fx = (u32)__float2int_rn(e * DEN_SCALE);
    int num_fx = __float2int_rn(e * xs * NUM_SCALE);
    atomicAdd(&acc[d], ((u64)(u32)num_fx << 32) | (u64)den_fx);
}

// ---------------- fallback gemv (also used alone in slow path) ----------------
__global__ void gemv_rowdot(const float* __restrict__ F, const float* __restrict__ W,
                            float* __restrict__ x, int n, int d) {
    int wave = (blockIdx.x * blockDim.x + threadIdx.x) >> 6;
    int lane = threadIdx.x & 63;
    if (wave >= n) return;
    const v4f* f4 = (const v4f*)(F + (size_t)wave * d);
    const v4f* w4 = (const v4f*)W;
    int nv = d >> 2;
    float s = 0.f;
    #pragma unroll 2
    for (int k = lane; k < nv; k += 64) {
        v4f a = __builtin_nontemporal_load(&f4[k]);
        v4f b = w4[k];
        s += a.x * b.x + a.y * b.y + a.z * b.z + a.w * b.w;
    }
    #pragma unroll
    for (int off = 32; off; off >>= 1) s += __shfl_down(s, off, 64);
    if (lane == 0) x[wave] = s;
}

// -------- Fused kernel: scatter blocks first (no x dependency), gemv blocks after.
// Scatter payload is 4B: {src:20 | dst_low:12}. All float work deferred to phase 2.
// Overflow (adversarial dst skew only) pushes {src,dst} to a list handled post-gemv.
__global__ __launch_bounds__(P1BLK)
void gemv_and_scatter(const float* __restrict__ F, const float* __restrict__ W,
                      float* __restrict__ x, int n, int d,
                      const int* __restrict__ ei, u32* __restrict__ binbuf,
                      u32* __restrict__ cnt, u64* __restrict__ ovf,
                      int nedges, int nb, int capb, int nsblk, u32 ovfcap) {
    if ((int)blockIdx.x >= nsblk) {
        // ---------------- gemv part: one wave per row ----------------
        int gblk = (int)blockIdx.x - nsblk;
        int wave = gblk * 4 + ((int)threadIdx.x >> 6);
        int lane = threadIdx.x & 63;
        if (wave >= n) return;
        const v4f* f4 = (const v4f*)(F + (size_t)wave * d);
        const v4f* w4 = (const v4f*)W;
        int nv = d >> 2;
        float s = 0.f;
        #pragma unroll 2
        for (int k = lane; k < nv; k += 64) {
            v4f a = __builtin_nontemporal_load(&f4[k]);
            v4f b = w4[k];
            s += a.x * b.x + a.y * b.y + a.z * b.z + a.w * b.w;
        }
        #pragma unroll
        for (int off = 32; off; off >>= 1) s += __shfl_down(s, off, 64);
        if (lane == 0) x[wave] = s;
        return;
    }
    // ---------------- scatter part ----------------
    __shared__ u32 lhist[MAXNB];
    __shared__ u32 lbase[MAXNB];
    const int tid = threadIdx.x;
    for (int b = tid; b < nb; b += P1BLK) lhist[b] = 0;
    __syncthreads();

    const long long base_e = (long long)blockIdx.x * CHUNK + (long long)tid * EPT;

    int se[EPT], de[EPT];
    if (((nedges & 3) == 0) && (base_e + EPT <= nedges)) {
        const v4i* sp = (const v4i*)(ei + base_e);
        const v4i* dp = (const v4i*)(ei + (size_t)nedges + base_e);
        #pragma unroll
        for (int q = 0; q < EPT / 4; ++q) {
            v4i a = __builtin_nontemporal_load(&sp[q]);
            v4i b = __builtin_nontemporal_load(&dp[q]);
            se[4 * q + 0] = a.x; se[4 * q + 1] = a.y;
            se[4 * q + 2] = a.z; se[4 * q + 3] = a.w;
            de[4 * q + 0] = b.x; de[4 * q + 1] = b.y;
            de[4 * q + 2] = b.z; de[4 * q + 3] = b.w;
        }
    } else {
        #pragma unroll
        for (int t = 0; t < EPT; ++t) {
            long long idx = base_e + t;
            if (idx < nedges) { se[t] = ei[idx]; de[t] = ei[(size_t)nedges + idx]; }
            else { se[t] = -1; de[t] = -1; }
        }
    }

    u32 pk[EPT], rk[EPT]; int bn[EPT];
    #pragma unroll
    for (int t = 0; t < EPT; ++t) {
        if (se[t] >= 0) {
            bn[t] = de[t] >> RBITS;
            pk[t] = ((u32)se[t] << RBITS) | (u32)(de[t] & (RSZ - 1));
            rk[t] = atomicAdd(&lhist[bn[t]], 1u);      // LDS arrival rank
        } else {
            bn[t] = -1;
        }
    }
    __syncthreads();
    if (tid < nb) lbase[tid] = atomicAdd(&cnt[tid], lhist[tid]);   // reserve window
    __syncthreads();
    #pragma unroll
    for (int t = 0; t < EPT; ++t) {
        if (bn[t] >= 0) {
            u32 slot = lbase[bn[t]] + rk[t];
            if (slot < (u32)capb) {
                binbuf[(size_t)bn[t] * (size_t)capb + slot] = pk[t];
            } else {
                u32 os = atomicAdd(&cnt[MAXNB], 1u);   // overflow counter
                if (os < ovfcap)
                    ovf[os] = ((u64)(u32)se[t] << 32) | (u64)(u32)de[t];
            }
        }
    }
}

// -------- Overflow fixup (normally zero work): far atomics into acc, after gemv ------
__global__ void overflow_fix(const u64* __restrict__ ovf, const u32* __restrict__ cnt,
                             const float* __restrict__ x,
                             const float* __restrict__ att_src_p,
                             const float* __restrict__ att_dst_p,
                             u64* __restrict__ acc, u32 ovfcap) {
    u32 m = cnt[MAXNB];
    if (m > ovfcap) m = ovfcap;
    float as = *att_src_p, ad = *att_dst_p;
    for (u32 i = blockIdx.x * blockDim.x + threadIdx.x; i < m;
         i += gridDim.x * blockDim.x) {
        u64 p = ovf[i];
        int s = (int)(p >> 32), dd = (int)(p & 0xFFFFFFFFull);
        edge_one(x[s], x[dd], as, ad, dd, acc);
    }
}

// -------- Phase 2: per-bin LDS accumulation. xd from LDS-staged bin slice of x,
// xs gathered from L2-resident x. u64 fixed-point LDS atomics (bit-exact sums).
__global__ __launch_bounds__(P2BLK)
void bin_reduce(const u32* __restrict__ binbuf, const u32* __restrict__ cnt,
                const float* __restrict__ x,
                const float* __restrict__ att_src_p, const float* __restrict__ att_dst_p,
                u64* __restrict__ partial, int n, int capb) {
    __shared__ u64 lacc[RSZ];            // 32 KB
    __shared__ float lx[RSZ];            // 16 KB bin slice of x
    const int b = blockIdx.x / SSUB;
    const int s = blockIdx.x % SSUB;
    const int tid = threadIdx.x;
    const int base = b << RBITS;
    #pragma unroll
    for (int r = tid; r < RSZ; r += P2BLK) {
        lacc[r] = 0ull;
        int idx = base + r;
        lx[r] = (idx < n) ? x[idx] : 0.f;
    }
    __syncthreads();

    const float as = *att_src_p, ad = *att_dst_p;
    u32 cb = cnt[b];
    if (cb > (u32)capb) cb = (u32)capb;
    u32 lo = (u32)(((u64)cb * (u32)s) / SSUB);
    u32 hi = (u32)(((u64)cb * (u32)(s + 1)) / SSUB);
    const u32* src = binbuf + (size_t)b * (size_t)capb;
    for (u32 k = lo + tid; k < hi; k += P2BLK) {
        u32 p = src[k];
        int sj   = (int)(p >> RBITS);
        int dlow = (int)(p & (RSZ - 1));
        float xs = x[sj];                 // L2 gather
        float xd = lx[dlow];              // LDS
        float v = xs * as + xd * ad;
        float logit = v > 0.f ? v : NEG_SLOPE * v;
        float e = __expf(logit);
        u32 den = (u32)__float2int_rn(e * DEN_SCALE);
        int num = __float2int_rn(e * xs * NUM_SCALE);
        atomicAdd(&lacc[dlow], ((u64)(u32)num << 32) | (u64)den);   // ds_add_u64
    }
    __syncthreads();
    u64* dstp = partial + (size_t)blockIdx.x * RSZ;
    #pragma unroll
    for (int r = tid; r < RSZ; r += P2BLK) dstp[r] = lacc[r];
}

// -------- Phase 3: sum SSUB partials + overflow acc + self-loop --------
__global__ void finalize2(const u64* __restrict__ partial, const u64* __restrict__ acc,
                          const float* __restrict__ x,
                          const float* __restrict__ att_src_p,
                          const float* __restrict__ att_dst_p,
                          const float* __restrict__ bias, float* __restrict__ out, int n) {
    int i = blockIdx.x * blockDim.x + threadIdx.x;
    if (i >= n) return;
    int b = i >> RBITS, r = i & (RSZ - 1);
    u64 t = acc[i];
    const u64* pp = partial + ((size_t)b * SSUB) * RSZ + r;
    #pragma unroll
    for (int s = 0; s < SSUB; ++s) t += pp[(size_t)s * RSZ];
    float xi = x[i];
    float v = xi * (*att_src_p + *att_dst_p);       // self-loop
    float logit = v > 0.f ? v : NEG_SLOPE * v;
    float es = __expf(logit);
    float num = (float)(int)(t >> 32) * INV_NUM_SCALE;
    float den = (float)(u32)(t & 0xFFFFFFFFull) * INV_DEN_SCALE;
    out[i] = (num + es * xi) / (den + es) + *bias;
}

// ================= fallback (ws too small / n too large): far-atomic path ===========
__global__ void edge_accum4(const int* __restrict__ ei, const float* __restrict__ x,
                            const float* __restrict__ att_src_p,
                            const float* __restrict__ att_dst_p,
                            u64* __restrict__ acc, int nedges) {
    int nq = nedges >> 2;
    int i = blockIdx.x * blockDim.x + threadIdx.x;
    if (i >= nq) return;
    const v4i* s4 = (const v4i*)ei;
    const v4i* d4 = (const v4i*)(ei + nedges);
    v4i s = s4[i], d = d4[i];
    float as = *att_src_p, ad = *att_dst_p;
    float xs0 = x[s.x], xs1 = x[s.y], xs2 = x[s.z], xs3 = x[s.w];
    float xd0 = x[d.x], xd1 = x[d.y], xd2 = x[d.z], xd3 = x[d.w];
    edge_one(xs0, xd0, as, ad, d.x, acc);
    edge_one(xs1, xd1, as, ad, d.y, acc);
    edge_one(xs2, xd2, as, ad, d.z, acc);
    edge_one(xs3, xd3, as, ad, d.w, acc);
}

__global__ void edge_accum1(const int* __restrict__ ei, const float* __restrict__ x,
                            const float* __restrict__ att_src_p,
                            const float* __restrict__ att_dst_p,
                            u64* __restrict__ acc, int nedges) {
    int i = blockIdx.x * blockDim.x + threadIdx.x;
    if (i >= nedges) return;
    int s = ei[i], d = ei[nedges + i];
    edge_one(x[s], x[d], *att_src_p, *att_dst_p, d, acc);
}

__global__ void finalize_atomic(const u64* __restrict__ acc, const float* __restrict__ x,
                                const float* __restrict__ att_src_p,
                                const float* __restrict__ att_dst_p,
                                const float* __restrict__ bias, float* __restrict__ out,
                                int n) {
    int i = blockIdx.x * blockDim.x + threadIdx.x;
    if (i >= n) return;
    float xi = x[i];
    float v = xi * (*att_src_p + *att_dst_p);
    float logit = v > 0.f ? v : NEG_SLOPE * v;
    float es = __expf(logit);
    u64 a = acc[i];
    float num = (float)(int)(a >> 32) * INV_NUM_SCALE;
    float den = (float)(u32)(a & 0xFFFFFFFFull) * INV_DEN_SCALE;
    out[i] = (num + es * xi) / (den + es) + *bias;
}

extern "C" void kernel_launch(void* const* d_in, const int* in_sizes, int n_in,
                              void* d_out, int out_size, void* d_ws, size_t ws_size,
                              hipStream_t stream) {
    const float* F       = (const float*)d_in[0];
    const int*   ei      = (const int*)d_in[1];
    const float* W       = (const float*)d_in[2];
    const float* att_src = (const float*)d_in[3];
    const float* att_dst = (const float*)d_in[4];
    const float* bias    = (const float*)d_in[5];
    float* out = (float*)d_out;

    int d = in_sizes[2];              // 512
    int n = in_sizes[0] / d;          // 100000
    int e = in_sizes[1] / 2;          // 6400000

    int nb = (n + RSZ - 1) >> RBITS;  // 25 bins
    // bin capacity: expected + ~6% + fixed slack (>>40 sigma for uniform dst)
    size_t capb_s = ((size_t)e * RSZ) / (size_t)(n > 0 ? n : 1);
    capb_s += capb_s / 16 + 4096;
    int capb = (int)capb_s;
    u32 ovfcap = (u32)e;

    // workspace layout
    size_t off_x   = 0;
    size_t off_acc = ((size_t)n * 4 + 7) & ~(size_t)7;
    size_t off_cnt = off_acc + (size_t)n * 8;                 // (MAXNB+1) u32 counters
    size_t off_par = (off_cnt + (size_t)(MAXNB + 1) * 4 + 7) & ~(size_t)7;
    size_t off_ovf = off_par + (size_t)nb * SSUB * RSZ * 8;
    size_t off_bin = off_ovf + (size_t)ovfcap * 8;
    size_t needed  = off_bin + (size_t)nb * capb_s * 4;

    float* x  = (float*)((char*)d_ws + off_x);
    u64* acc  = (u64*)((char*)d_ws + off_acc);
    u32* cnt  = (u32*)((char*)d_ws + off_cnt);
    u64* par  = (u64*)((char*)d_ws + off_par);
    u64* ovf  = (u64*)((char*)d_ws + off_ovf);
    u32* bin  = (u32*)((char*)d_ws + off_bin);

    bool fast = (nb <= MAXNB) && (n <= (1 << (32 - RBITS))) &&
                (needed <= ws_size) && (e > 0) && (n > 0);

    if (fast) {
        // zero acc + all counters in one memset (contiguous)
        (void)hipMemsetAsync(acc, 0, (size_t)n * 8 + (size_t)(MAXNB + 1) * 4, stream);
        int nsblk = (int)(((long long)e + CHUNK - 1) / CHUNK);    // scatter blocks
        int ngblk = (n + 3) / 4;                                  // gemv blocks
        gemv_and_scatter<<<nsblk + ngblk, P1BLK, 0, stream>>>(
            F, W, x, n, d, ei, bin, cnt, ovf, e, nb, capb, nsblk, ovfcap);
        overflow_fix<<<256, 256, 0, stream>>>(ovf, cnt, x, att_src, att_dst, acc, ovfcap);
        bin_reduce<<<nb * SSUB, P2BLK, 0, stream>>>(bin, cnt, x, att_src, att_dst,
                                                    par, n, capb);
        finalize2<<<(n + 255) / 256, 256, 0, stream>>>(par, acc, x, att_src, att_dst,
                                                       bias, out, n);
    } else {
        (void)hipMemsetAsync(acc, 0, (size_t)n * 8, stream);
        gemv_rowdot<<<(n + 3) / 4, 256, 0, stream>>>(F, W, x, n, d);
        if (e > 0) {
            if ((e & 3) == 0) {
                edge_accum4<<<((e >> 2) + 255) / 256, 256, 0, stream>>>(
                    ei, x, att_src, att_dst, acc, e);
            } else {
                edge_accum1<<<(e + 255) / 256, 256, 0, stream>>>(
                    ei, x, att_src, att_dst, acc, e);
            }
        }
        finalize_atomic<<<(n + 255) / 256, 256, 0, stream>>>(acc, x, att_src, att_dst,
                                                             bias, out, n);
    }
}